// Round 1
// baseline (212.259 us; speedup 1.0000x reference)
//
#include <hip/hip_runtime.h>
#include <math.h>

#define D     1024
#define CD    16
#define CS    8192
#define ROWS  16384   // B*L = 8*2048
#define LN_EPS 1e-5f
#define CHUNK 512
#define NCHUNK (CS / CHUNK)   // 16

// -------------------------------------------------------------------------
// Kernel 1: z = LayerNorm(x @ W^T)   (16384 rows, 16 channels)
// 1024 blocks x 256 threads; thread t -> channel c = t&15, local row = t>>4.
// W (16x1024, 64KB) staged in LDS with XOR swizzle on float4 granules:
// granule (c,g) stored at word c*1024 + 4*(g ^ (c&7)). Natural layout would
// put all 16 channels of a given k on one bank (16-way conflict); the swizzle
// spreads them over 8 bank-groups (2-way, which is free on CDNA4).
// -------------------------------------------------------------------------
__global__ __launch_bounds__(256) void proj_ln(const float* __restrict__ x,
                                               const float* __restrict__ W,
                                               float* __restrict__ z)
{
    __shared__ float wl[CD * D];   // 64 KB
    const int t = threadIdx.x;

    // stage W: 4096 float4 granules, 16 per thread
    const float4* w4 = (const float4*)W;
    for (int i = 0; i < 16; ++i) {
        int q = t + i * 256;          // linear granule 0..4095
        int c = q >> 8;               // 256 granules per channel row
        int g = q & 255;
        float4 v = w4[q];
        *((float4*)&wl[c * 1024 + 4 * (g ^ (c & 7))]) = v;
    }
    __syncthreads();

    const int c  = t & 15;
    const int rl = t >> 4;
    const long row = (long)blockIdx.x * 16 + rl;
    const float4* xr = (const float4*)(x + row * D);

    const int cbase = c * 1024;
    const int cx    = c & 7;
    float acc = 0.f;
    #pragma unroll 4
    for (int g = 0; g < 256; ++g) {
        float4 xv = xr[g];                                   // 16 lanes share addr
        float4 wv = *((const float4*)&wl[cbase + 4 * (g ^ cx)]);
        acc = fmaf(xv.x, wv.x, acc);
        acc = fmaf(xv.y, wv.y, acc);
        acc = fmaf(xv.z, wv.z, acc);
        acc = fmaf(xv.w, wv.w, acc);
    }

    // LayerNorm over the 16-lane channel group (xor masks 1,2,4,8 stay in-group)
    float s = acc;
    for (int m = 1; m < 16; m <<= 1) s += __shfl_xor(s, m, 64);
    float mu = s * (1.f / 16.f);
    float d  = acc - mu;
    float v2 = d * d;
    for (int m = 1; m < 16; m <<= 1) v2 += __shfl_xor(v2, m, 64);
    float var = v2 * (1.f / 16.f);
    z[row * CD + c] = d / sqrtf(var + LN_EPS);
}

// -------------------------------------------------------------------------
// Kernel 2: csq2[k] = 0.5 * ||codebook[k]||^2
// -------------------------------------------------------------------------
__global__ __launch_bounds__(256) void csqk(const float* __restrict__ cb,
                                            float* __restrict__ csq2)
{
    int k = blockIdx.x * 256 + threadIdx.x;   // 0..8191
    const float4* c4 = (const float4*)(cb + (long)k * CD);
    float4 a = c4[0], b = c4[1], c = c4[2], e = c4[3];
    float s0 = a.x*a.x + a.y*a.y + a.z*a.z + a.w*a.w;
    float s1 = b.x*b.x + b.y*b.y + b.z*b.z + b.w*b.w;
    float s2 = c.x*c.x + c.y*c.y + c.z*c.z + c.w*c.w;
    float s3 = e.x*e.x + e.y*e.y + e.z*e.z + e.w*e.w;
    csq2[k] = 0.5f * ((s0 + s1) + (s2 + s3));
}

// -------------------------------------------------------------------------
// Kernel 3: partial argmax of score s_k = z.c_k - 0.5*||c_k||^2
// grid (64 row-blocks, 16 code-chunks) x 256 threads; thread = one row.
// Codebook chunk (512x16 = 32KB) + csq2 chunk (2KB) staged in LDS; inner
// reads are wave-uniform addresses -> broadcast, conflict-free.
// argmin d2 == argmax s; ascending k + strict '>' preserves first-min
// tie-breaking of the reference.
// -------------------------------------------------------------------------
__global__ __launch_bounds__(256) void dist_argmin(const float* __restrict__ z,
                                                   const float* __restrict__ cb,
                                                   const float* __restrict__ csq2,
                                                   float* __restrict__ pbest,
                                                   int* __restrict__ pidx)
{
    __shared__ float cl[CHUNK * CD];   // 32 KB
    __shared__ float ql[CHUNK];        // 2 KB
    const int t = threadIdx.x;
    const int kbase = blockIdx.y * CHUNK;

    const float4* src = (const float4*)(cb + (long)kbase * CD);
    float4* dst = (float4*)cl;
    #pragma unroll
    for (int i = 0; i < 8; ++i) dst[t + i * 256] = src[t + i * 256];
    if (t < CHUNK / 4) ((float4*)ql)[t] = ((const float4*)(csq2 + kbase))[t];
    __syncthreads();

    const long row = (long)blockIdx.x * 256 + t;
    const float4* zr = (const float4*)(z + row * CD);
    float4 z0 = zr[0], z1 = zr[1], z2 = zr[2], z3 = zr[3];

    float best = -INFINITY;
    int   bi   = 0;
    #pragma unroll 4
    for (int k = 0; k < CHUNK; ++k) {
        const float4* c4 = (const float4*)&cl[k * CD];
        float4 c0 = c4[0], c1 = c4[1], c2 = c4[2], c3 = c4[3];
        float s = -ql[k];
        s = fmaf(z0.x, c0.x, s); s = fmaf(z0.y, c0.y, s);
        s = fmaf(z0.z, c0.z, s); s = fmaf(z0.w, c0.w, s);
        s = fmaf(z1.x, c1.x, s); s = fmaf(z1.y, c1.y, s);
        s = fmaf(z1.z, c1.z, s); s = fmaf(z1.w, c1.w, s);
        s = fmaf(z2.x, c2.x, s); s = fmaf(z2.y, c2.y, s);
        s = fmaf(z2.z, c2.z, s); s = fmaf(z2.w, c2.w, s);
        s = fmaf(z3.x, c3.x, s); s = fmaf(z3.y, c3.y, s);
        s = fmaf(z3.z, c3.z, s); s = fmaf(z3.w, c3.w, s);
        if (s > best) { best = s; bi = k; }
    }
    pbest[row * NCHUNK + blockIdx.y] = best;
    pidx [row * NCHUNK + blockIdx.y] = kbase + bi;
}

// -------------------------------------------------------------------------
// Kernel 4: merge 16 partials per row (ascending chunk order = ascending
// code index, strict '>' keeps the earliest -> matches np first-min argmin).
// -------------------------------------------------------------------------
__global__ __launch_bounds__(256) void merge_argmin(const float* __restrict__ pbest,
                                                    const int* __restrict__ pidx,
                                                    int* __restrict__ out)
{
    const long row = (long)blockIdx.x * 256 + threadIdx.x;
    float best = -INFINITY;
    int   bi   = 0;
    #pragma unroll
    for (int i = 0; i < NCHUNK; ++i) {
        float s = pbest[row * NCHUNK + i];
        if (s > best) { best = s; bi = pidx[row * NCHUNK + i]; }
    }
    out[row] = bi;
}

// -------------------------------------------------------------------------
extern "C" void kernel_launch(void* const* d_in, const int* in_sizes, int n_in,
                              void* d_out, int out_size, void* d_ws, size_t ws_size,
                              hipStream_t stream)
{
    const float* x  = (const float*)d_in[0];   // 8*2048*1024
    const float* W  = (const float*)d_in[1];   // 16*1024
    const float* cb = (const float*)d_in[2];   // 8192*16
    int* out = (int*)d_out;                    // 16384 int32 codes

    char* ws = (char*)d_ws;
    float* z     = (float*)ws;                                  // 1 MB
    float* csq2  = (float*)(ws + (1 << 20));                    // 32 KB
    float* pbest = (float*)(ws + (1 << 20) + (1 << 15));        // 1 MB
    int*   pidx  = (int*)  (ws + (2 << 20) + (1 << 15));        // 1 MB

    proj_ln<<<ROWS / 16, 256, 0, stream>>>(x, W, z);
    csqk<<<CS / 256, 256, 0, stream>>>(cb, csq2);
    dist_argmin<<<dim3(ROWS / 256, NCHUNK), 256, 0, stream>>>(z, cb, csq2, pbest, pidx);
    merge_argmin<<<ROWS / 256, 256, 0, stream>>>(pbest, pidx, out);
}

// Round 2
// 172.259 us; speedup vs baseline: 1.2322x; 1.2322x over previous
//
#include <hip/hip_runtime.h>
#include <math.h>

#define D      1024
#define CD     16
#define CS     8192
#define ROWS   16384   // B*L
#define LN_EPS 1e-5f
#define KCHUNK 512            // codes per dist chunk
#define NCHUNK (CS / KCHUNK)  // 16

typedef __attribute__((ext_vector_type(8))) short short8;
typedef __attribute__((ext_vector_type(4))) float f32x4;

// exact RNE fp32->bf16 on bit level (inputs finite)
__device__ inline unsigned short bf16_rne(float v) {
    unsigned u = __float_as_uint(v);
    unsigned r = u + 0x7FFFu + ((u >> 16) & 1u);
    return (unsigned short)(r >> 16);
}
__device__ inline float bf16_f(unsigned short s) {
    return __uint_as_float(((unsigned)s) << 16);
}
__device__ inline short8 ld8(const unsigned short* p) { return *(const short8*)p; }

// -------------------------------------------------------------------------
// Kernel 1: z = LayerNorm(x @ W^T), emitted as 3-term bf16 split (48 bf16/row).
// 512 thr/block (32 rows), W in 64KB LDS XOR-swizzled (2-way = free).
// 2 blocks/CU resident -> 16 waves/CU; unroll 8 for memory parallelism.
// -------------------------------------------------------------------------
__global__ __launch_bounds__(512, 4) void proj_ln(const float* __restrict__ x,
                                                  const float* __restrict__ W,
                                                  unsigned short* __restrict__ zp)
{
    __shared__ float wl[CD * D];   // 64 KB
    const int t = threadIdx.x;
    const float4* w4 = (const float4*)W;
    #pragma unroll
    for (int i = 0; i < 8; ++i) {
        int qg = t + i * 512;          // granule 0..4095
        int c = qg >> 8;
        int g = qg & 255;
        float4 v = w4[qg];
        *((float4*)&wl[c * 1024 + 4 * (g ^ (c & 7))]) = v;
    }
    __syncthreads();

    const int c  = t & 15;
    const int rl = t >> 4;                       // 0..31
    const long row = (long)blockIdx.x * 32 + rl;
    const float4* xr = (const float4*)(x + row * D);
    const int cbase = c * 1024;
    const int cx = c & 7;
    float acc = 0.f;
    #pragma unroll 8
    for (int g = 0; g < 256; ++g) {
        float4 xv = xr[g];                                   // 16 lanes broadcast
        float4 wv = *((const float4*)&wl[cbase + 4 * (g ^ cx)]);
        acc = fmaf(xv.x, wv.x, acc);
        acc = fmaf(xv.y, wv.y, acc);
        acc = fmaf(xv.z, wv.z, acc);
        acc = fmaf(xv.w, wv.w, acc);
    }

    float s = acc;
    for (int m = 1; m < 16; m <<= 1) s += __shfl_xor(s, m, 64);
    float mu = s * (1.f / 16.f);
    float d  = acc - mu;
    float v2 = d * d;
    for (int m = 1; m < 16; m <<= 1) v2 += __shfl_xor(v2, m, 64);
    float var = v2 * (1.f / 16.f);
    float z = d / sqrtf(var + LN_EPS);

    // exact 3-term bf16 split: z = z0 + z1 + z2 (residual ~2^-27 relative)
    unsigned short h0 = bf16_rne(z);
    float r1 = z - bf16_f(h0);
    unsigned short h1 = bf16_rne(r1);
    float r2 = r1 - bf16_f(h1);
    unsigned short h2 = bf16_rne(r2);
    unsigned short* zr = zp + row * 48;
    zr[c] = h0; zr[16 + c] = h1; zr[32 + c] = h2;
}

// -------------------------------------------------------------------------
// Kernel 2: pack codebook to 3-term bf16 split (48 bf16/code) + nhc = -0.5*||c||^2
// -------------------------------------------------------------------------
__global__ __launch_bounds__(256) void pack_cb(const float* __restrict__ cb,
                                               unsigned short* __restrict__ cbp,
                                               float* __restrict__ nhc)
{
    int k = blockIdx.x * 256 + threadIdx.x;    // 0..8191
    const float* c = cb + (long)k * CD;
    unsigned short* o = cbp + (long)k * 48;
    float csq = 0.f;
    #pragma unroll
    for (int d = 0; d < 16; ++d) {
        float v = c[d];
        csq = fmaf(v, v, csq);
        unsigned short h0 = bf16_rne(v);
        float r1 = v - bf16_f(h0);
        unsigned short h1 = bf16_rne(r1);
        float r2 = r1 - bf16_f(h1);
        o[d] = h0; o[16 + d] = h1; o[32 + d] = bf16_rne(r2);
    }
    nhc[k] = -0.5f * csq;
}

// -------------------------------------------------------------------------
// Kernel 3: MFMA distance+argmax.  score = z.c - 0.5||c||^2, argmin d2 = argmax s.
// fp32-grade accuracy via 3 packed mfma_f32_16x16x32_bf16 per 16x16 tile:
//   [z0|z1].[c0|c1] + [z0|z1].[c1|c0] + [z0|z2].[c2|c0]
//     = z0c0+z1c1 + z0c1+z1c0 + z0c2+z2c0   (all terms >= 2^-24; dropped ~2^-27)
// Bias preloaded into the accumulator.  Each wave: 4 row-tiles (64 rows) so
// each B-fragment LDS read feeds 12 MFMAs.  Block = 4 waves, 512-code chunk
// staged in 48KB LDS -> 3 blocks/CU.
// A-frag: A[m=lane&15][k=quad*8+j]; C/D: col=lane&15 (code), row=quad*4+reg.
// -------------------------------------------------------------------------
__global__ __launch_bounds__(256, 3) void dist_argmin(const unsigned short* __restrict__ zp,
                                                      const unsigned short* __restrict__ cbp,
                                                      const float* __restrict__ nhc,
                                                      float* __restrict__ pbest,
                                                      int* __restrict__ pidx)
{
    __shared__ __align__(16) unsigned short cl[KCHUNK * 48];  // 48 KB
    __shared__ float ql[KCHUNK];                              // 2 KB
    const int t = threadIdx.x;
    const int kbase = blockIdx.y * KCHUNK;

    {
        float4* dst = (float4*)cl;
        const float4* src = (const float4*)(cbp + (size_t)kbase * 48);
        #pragma unroll
        for (int i = 0; i < 12; ++i) dst[t + i * 256] = src[t + i * 256];
        if (t < KCHUNK / 4) ((float4*)ql)[t] = ((const float4*)(nhc + kbase))[t];
    }
    __syncthreads();

    const int L = t & 63;
    const int w = t >> 6;
    const int n = L & 15;    // code col (B) / row m (A)
    const int q = L >> 4;    // quad

    // A fragments for this wave's 4 row-tiles
    short8 a1[4], a2[4];
    const int rt0 = blockIdx.x * 16 + w * 4;
    #pragma unroll
    for (int j = 0; j < 4; ++j) {
        const unsigned short* zr = zp + (size_t)((rt0 + j) * 16 + n) * 48;
        a1[j] = ld8(zr + q * 8);                            // [z0|z1]
        a2[j] = ld8(zr + (q < 2 ? q * 8 : 16 + q * 8));     // [z0|z2]
    }

    float best[4][4];
    int   bi[4][4];
    #pragma unroll
    for (int j = 0; j < 4; ++j)
        #pragma unroll
        for (int r = 0; r < 4; ++r) { best[j][r] = -INFINITY; bi[j][r] = 0; }

    const int o1 = q * 8;                           // [c0|c1]
    const int o2 = (q * 8 + 16) & 31;               // [c1|c0]
    const int o3 = q < 2 ? 32 + q * 8 : (q - 2) * 8; // [c2|c0]

    for (int tt = 0; tt < KCHUNK / 16; ++tt) {
        const unsigned short* cb_t = cl + (size_t)(tt * 16 + n) * 48;
        short8 b1 = ld8(cb_t + o1);
        short8 b2 = ld8(cb_t + o2);
        short8 b3 = ld8(cb_t + o3);
        float bneg = ql[tt * 16 + n];
        int code = kbase + tt * 16 + n;
        #pragma unroll
        for (int j = 0; j < 4; ++j) {
            f32x4 acc = {bneg, bneg, bneg, bneg};
            acc = __builtin_amdgcn_mfma_f32_16x16x32_bf16(a1[j], b1, acc, 0, 0, 0);
            acc = __builtin_amdgcn_mfma_f32_16x16x32_bf16(a1[j], b2, acc, 0, 0, 0);
            acc = __builtin_amdgcn_mfma_f32_16x16x32_bf16(a2[j], b3, acc, 0, 0, 0);
            #pragma unroll
            for (int r = 0; r < 4; ++r)
                if (acc[r] > best[j][r]) { best[j][r] = acc[r]; bi[j][r] = code; }
        }
    }

    // reduce across the 16 code-columns (lanes n=0..15 within each quad)
    #pragma unroll
    for (int mask = 1; mask < 16; mask <<= 1) {
        #pragma unroll
        for (int j = 0; j < 4; ++j)
            #pragma unroll
            for (int r = 0; r < 4; ++r) {
                float s2 = __shfl_xor(best[j][r], mask, 64);
                int   i2 = __shfl_xor(bi[j][r], mask, 64);
                if (s2 > best[j][r] || (s2 == best[j][r] && i2 < bi[j][r])) {
                    best[j][r] = s2; bi[j][r] = i2;
                }
            }
    }
    if (n == 0) {
        #pragma unroll
        for (int j = 0; j < 4; ++j)
            #pragma unroll
            for (int r = 0; r < 4; ++r) {
                int row = (rt0 + j) * 16 + q * 4 + r;
                pbest[(size_t)row * NCHUNK + blockIdx.y] = best[j][r];
                pidx [(size_t)row * NCHUNK + blockIdx.y] = bi[j][r];
            }
    }
}

// -------------------------------------------------------------------------
// Kernel 4: merge 16 partials/row; ascending chunk order + strict '>' keeps
// the earliest (first-min) winner, matching np.argmin.
// -------------------------------------------------------------------------
__global__ __launch_bounds__(256) void merge_argmin(const float* __restrict__ pbest,
                                                    const int* __restrict__ pidx,
                                                    int* __restrict__ out)
{
    const long row = (long)blockIdx.x * 256 + threadIdx.x;
    float best = -INFINITY;
    int   bi   = 0;
    #pragma unroll
    for (int i = 0; i < NCHUNK; ++i) {
        float s = pbest[row * NCHUNK + i];
        if (s > best) { best = s; bi = pidx[row * NCHUNK + i]; }
    }
    out[row] = bi;
}

// -------------------------------------------------------------------------
extern "C" void kernel_launch(void* const* d_in, const int* in_sizes, int n_in,
                              void* d_out, int out_size, void* d_ws, size_t ws_size,
                              hipStream_t stream)
{
    const float* x  = (const float*)d_in[0];   // 8*2048*1024
    const float* W  = (const float*)d_in[1];   // 16*1024
    const float* cb = (const float*)d_in[2];   // 8192*16
    int* out = (int*)d_out;                    // 16384 int32

    char* ws = (char*)d_ws;
    unsigned short* zp  = (unsigned short*)ws;              // 16384*48*2 = 1.5 MB
    unsigned short* cbp = (unsigned short*)(ws + 0x180000); // 8192*48*2 = 768 KB
    float* nhc   = (float*)(ws + 0x240000);                 // 32 KB
    float* pbest = (float*)(ws + 0x248000);                 // 1 MB
    int*   pidx  = (int*)  (ws + 0x348000);                 // 1 MB

    proj_ln<<<ROWS / 32, 512, 0, stream>>>(x, W, zp);
    pack_cb<<<CS / 256, 256, 0, stream>>>(cb, cbp, nhc);
    dist_argmin<<<dim3(ROWS / 256, NCHUNK), 256, 0, stream>>>(zp, cbp, nhc, pbest, pidx);
    merge_argmin<<<ROWS / 256, 256, 0, stream>>>(pbest, pidx, out);
}

// Round 3
// 142.663 us; speedup vs baseline: 1.4878x; 1.2074x over previous
//
#include <hip/hip_runtime.h>
#include <math.h>

#define D      1024
#define CD     16
#define CS     8192
#define ROWS   16384   // B*L
#define LN_EPS 1e-5f
#define KCHUNK 512            // codes per dist chunk
#define NCHUNK (CS / KCHUNK)  // 16
#define KSPLIT 4              // proj K quarters (256 k each)

typedef __attribute__((ext_vector_type(8))) short short8;
typedef __attribute__((ext_vector_type(4))) float f32x4;

__device__ inline unsigned short bf16_rne(float v) {
    unsigned u = __float_as_uint(v);
    unsigned r = u + 0x7FFFu + ((u >> 16) & 1u);
    return (unsigned short)(r >> 16);
}
__device__ inline float bf16_f(unsigned short s) {
    return __uint_as_float(((unsigned)s) << 16);
}
__device__ inline short8 ld8(const unsigned short* p) { return *(const short8*)p; }

// exact 3-term bf16 split: v = a + b + c + O(2^-24 rel of v's ulp chain)
__device__ inline void split3(float v, unsigned short& a, unsigned short& b, unsigned short& c) {
    unsigned u = __float_as_uint(v);
    unsigned r = u + 0x7FFFu + ((u >> 16) & 1u);
    a = (unsigned short)(r >> 16);
    float r1 = v - __uint_as_float(r & 0xFFFF0000u);     // exact
    unsigned u1 = __float_as_uint(r1);
    unsigned r1b = u1 + 0x7FFFu + ((u1 >> 16) & 1u);
    b = (unsigned short)(r1b >> 16);
    float r2 = r1 - __uint_as_float(r1b & 0xFFFF0000u);  // exact
    c = bf16_rne(r2);
}

// -------------------------------------------------------------------------
// pack_w: W (16x1024 fp32) -> wb, 3-term bf16 split in MFMA-B-frag stream
// order: wb[((gk*3 + term)*64 + lane)*8 + j] = W_term[n=lane&15][gk*32+(lane>>4)*8+j]
// so projA reads one coalesced 1KB b128 load per (k-step, term).
// -------------------------------------------------------------------------
__global__ __launch_bounds__(256) void pack_w(const float* __restrict__ W,
                                              unsigned short* __restrict__ wb)
{
    int tid = blockIdx.x * 256 + threadIdx.x;    // 0..6143
    int gk   = tid / 192;
    int rem  = tid % 192;
    int term = rem >> 6;
    int L    = rem & 63;
    int n = L & 15, q = L >> 4;
    const float* src = W + n * D + gk * 32 + q * 8;
    unsigned short* dst = wb + (size_t)tid * 8;
    #pragma unroll
    for (int j = 0; j < 8; ++j) {
        unsigned short h0, h1, h2;
        split3(src[j], h0, h1, h2);
        dst[j] = term == 0 ? h0 : (term == 1 ? h1 : h2);
    }
}

// -------------------------------------------------------------------------
// projA: partial z = x @ W^T via MFMA, 3-term bf16 split both sides (6 MFMAs
// per 32-k step keep all products >= 2^-26 rel: x0w0,x0w1,x1w0,x1w1,x0w2,x2w0).
// Block = 1 row-tile (16 rows), 4 waves = 4 K-quarters (256 k each).
// 1024 blocks -> 16 waves/CU. x read directly from global (A-frag addresses;
// L1 merges the half-line pairs). W-frags stream from L2 (96KB, hot).
// -------------------------------------------------------------------------
__global__ __launch_bounds__(256) void projA(const float* __restrict__ x,
                                             const unsigned short* __restrict__ wb,
                                             float* __restrict__ zpart)
{
    const int t = threadIdx.x;
    const int L = t & 63;
    const int kq = t >> 6;                 // K-quarter
    const int rt = blockIdx.x;             // row-tile
    const int m = L & 15, q = L >> 4;
    const float* xrow = x + (size_t)(rt * 16 + m) * D + kq * 256 + q * 8;
    const unsigned short* wbase = wb + (size_t)(kq * 8) * 1536;  // gk = kq*8+kk

    f32x4 acc = {0.f, 0.f, 0.f, 0.f};
    #pragma unroll 2
    for (int kk = 0; kk < 8; ++kk) {
        float4 xa = *(const float4*)(xrow + kk * 32);
        float4 xb = *(const float4*)(xrow + kk * 32 + 4);
        const unsigned short* wp = wbase + (size_t)kk * 1536 + L * 8;
        short8 w0 = ld8(wp);
        short8 w1 = ld8(wp + 512);
        short8 w2 = ld8(wp + 1024);
        float vs[8] = {xa.x, xa.y, xa.z, xa.w, xb.x, xb.y, xb.z, xb.w};
        short8 x0, x1, x2;
        #pragma unroll
        for (int j = 0; j < 8; ++j) {
            unsigned short h0, h1, h2;
            split3(vs[j], h0, h1, h2);
            x0[j] = (short)h0; x1[j] = (short)h1; x2[j] = (short)h2;
        }
        acc = __builtin_amdgcn_mfma_f32_16x16x32_bf16(x0, w0, acc, 0, 0, 0);
        acc = __builtin_amdgcn_mfma_f32_16x16x32_bf16(x0, w1, acc, 0, 0, 0);
        acc = __builtin_amdgcn_mfma_f32_16x16x32_bf16(x1, w0, acc, 0, 0, 0);
        acc = __builtin_amdgcn_mfma_f32_16x16x32_bf16(x1, w1, acc, 0, 0, 0);
        acc = __builtin_amdgcn_mfma_f32_16x16x32_bf16(x0, w2, acc, 0, 0, 0);
        acc = __builtin_amdgcn_mfma_f32_16x16x32_bf16(x2, w0, acc, 0, 0, 0);
    }
    // C/D: col = lane&15 (channel), row = q*4 + r
    #pragma unroll
    for (int r = 0; r < 4; ++r)
        zpart[((size_t)kq * ROWS + rt * 16 + q * 4 + r) * CD + m] = acc[r];
}

// -------------------------------------------------------------------------
// projB: sum 4 K-partials, LayerNorm over 16 ch, emit 3-term bf16 split zp.
// -------------------------------------------------------------------------
__global__ __launch_bounds__(256) void projB(const float* __restrict__ zpart,
                                             unsigned short* __restrict__ zp)
{
    const int t = threadIdx.x;
    const int c = t & 15;
    const int rl = t >> 4;
    const size_t row = (size_t)blockIdx.x * 16 + rl;
    float z = 0.f;
    #pragma unroll
    for (int kq = 0; kq < KSPLIT; ++kq)
        z += zpart[((size_t)kq * ROWS + row) * CD + c];

    float s = z;
    for (int m = 1; m < 16; m <<= 1) s += __shfl_xor(s, m, 64);
    float mu = s * (1.f / 16.f);
    float d  = z - mu;
    float v2 = d * d;
    for (int m = 1; m < 16; m <<= 1) v2 += __shfl_xor(v2, m, 64);
    float var = v2 * (1.f / 16.f);
    float zn = d / sqrtf(var + LN_EPS);

    unsigned short h0, h1, h2;
    split3(zn, h0, h1, h2);
    unsigned short* zr = zp + row * 48;
    zr[c] = h0; zr[16 + c] = h1; zr[32 + c] = h2;
}

// -------------------------------------------------------------------------
// pack_cb: codebook -> 3-term bf16 split (48 bf16/code) + nhc = -0.5*||c||^2
// -------------------------------------------------------------------------
__global__ __launch_bounds__(256) void pack_cb(const float* __restrict__ cb,
                                               unsigned short* __restrict__ cbp,
                                               float* __restrict__ nhc)
{
    int k = blockIdx.x * 256 + threadIdx.x;    // 0..8191
    const float* c = cb + (long)k * CD;
    unsigned short* o = cbp + (long)k * 48;
    float csq = 0.f;
    #pragma unroll
    for (int d = 0; d < 16; ++d) {
        float v = c[d];
        csq = fmaf(v, v, csq);
        unsigned short h0, h1, h2;
        split3(v, h0, h1, h2);
        o[d] = h0; o[16 + d] = h1; o[32 + d] = h2;
    }
    nhc[k] = -0.5f * csq;
}

// -------------------------------------------------------------------------
// dist_argmin: score = z.c - 0.5||c||^2 (argmin d2 == argmax score).
// 3 packed mfma_f32_16x16x32_bf16 per 16x16 tile:
//   [z0|z1].[c0|c1] + [z0|z1].[c1|c0] + [z0|z2].[c2|c0]
// Block = 512 thr (8 waves), 512 rows; each wave 4 row-tiles. Grid 32x16 =
// 512 blocks = exactly 2 blocks/CU resident (one generation, no tail).
// Term-major MFMA passes give 4 independent acc chains between scans.
// -------------------------------------------------------------------------
__global__ __launch_bounds__(512, 4) void dist_argmin(const unsigned short* __restrict__ zp,
                                                      const unsigned short* __restrict__ cbp,
                                                      const float* __restrict__ nhc,
                                                      float* __restrict__ pbest,
                                                      int* __restrict__ pidx)
{
    __shared__ __align__(16) unsigned short cl[KCHUNK * 48];  // 48 KB
    __shared__ float ql[KCHUNK];                              // 2 KB
    const int t = threadIdx.x;
    const int kbase = blockIdx.y * KCHUNK;

    {
        float4* dst = (float4*)cl;
        const float4* src = (const float4*)(cbp + (size_t)kbase * 48);
        #pragma unroll
        for (int i = 0; i < 6; ++i) dst[t + i * 512] = src[t + i * 512];
        if (t < KCHUNK / 4) ((float4*)ql)[t] = ((const float4*)(nhc + kbase))[t];
    }
    __syncthreads();

    const int L = t & 63;
    const int w = t >> 6;
    const int n = L & 15;    // code col (B) / row m (A)
    const int q = L >> 4;    // quad

    short8 a1[4], a2[4];
    const int rt0 = blockIdx.x * 32 + w * 4;
    #pragma unroll
    for (int j = 0; j < 4; ++j) {
        const unsigned short* zr = zp + (size_t)((rt0 + j) * 16 + n) * 48;
        a1[j] = ld8(zr + q * 8);                            // [z0|z1]
        a2[j] = ld8(zr + (q < 2 ? q * 8 : 16 + q * 8));     // [z0|z2]
    }

    float best[4][4];
    int   bi[4][4];
    #pragma unroll
    for (int j = 0; j < 4; ++j)
        #pragma unroll
        for (int r = 0; r < 4; ++r) { best[j][r] = -INFINITY; bi[j][r] = 0; }

    const int o1 = q * 8;                            // [c0|c1]
    const int o2 = (q * 8 + 16) & 31;                // [c1|c0]
    const int o3 = q < 2 ? 32 + q * 8 : (q - 2) * 8; // [c2|c0]

    for (int tt = 0; tt < KCHUNK / 16; ++tt) {
        const unsigned short* cb_t = cl + (size_t)(tt * 16 + n) * 48;
        short8 b1 = ld8(cb_t + o1);
        short8 b2 = ld8(cb_t + o2);
        short8 b3 = ld8(cb_t + o3);
        float bneg = ql[tt * 16 + n];
        int code = kbase + tt * 16 + n;
        f32x4 acc[4];
        #pragma unroll
        for (int j = 0; j < 4; ++j) acc[j] = (f32x4){bneg, bneg, bneg, bneg};
        #pragma unroll
        for (int j = 0; j < 4; ++j)
            acc[j] = __builtin_amdgcn_mfma_f32_16x16x32_bf16(a1[j], b1, acc[j], 0, 0, 0);
        #pragma unroll
        for (int j = 0; j < 4; ++j)
            acc[j] = __builtin_amdgcn_mfma_f32_16x16x32_bf16(a1[j], b2, acc[j], 0, 0, 0);
        #pragma unroll
        for (int j = 0; j < 4; ++j)
            acc[j] = __builtin_amdgcn_mfma_f32_16x16x32_bf16(a2[j], b3, acc[j], 0, 0, 0);
        #pragma unroll
        for (int j = 0; j < 4; ++j)
            #pragma unroll
            for (int r = 0; r < 4; ++r)
                if (acc[j][r] > best[j][r]) { best[j][r] = acc[j][r]; bi[j][r] = code; }
    }

    // reduce across the 16 code-columns (lanes n within each quad)
    #pragma unroll
    for (int mask = 1; mask < 16; mask <<= 1) {
        #pragma unroll
        for (int j = 0; j < 4; ++j)
            #pragma unroll
            for (int r = 0; r < 4; ++r) {
                float s2 = __shfl_xor(best[j][r], mask, 64);
                int   i2 = __shfl_xor(bi[j][r], mask, 64);
                if (s2 > best[j][r] || (s2 == best[j][r] && i2 < bi[j][r])) {
                    best[j][r] = s2; bi[j][r] = i2;
                }
            }
    }
    if (n == 0) {
        #pragma unroll
        for (int j = 0; j < 4; ++j)
            #pragma unroll
            for (int r = 0; r < 4; ++r) {
                int row = (rt0 + j) * 16 + q * 4 + r;
                pbest[(size_t)row * NCHUNK + blockIdx.y] = best[j][r];
                pidx [(size_t)row * NCHUNK + blockIdx.y] = bi[j][r];
            }
    }
}

// -------------------------------------------------------------------------
// merge: fold 16 partials/row; ascending chunk order + strict '>' keeps the
// earliest winner -> matches np first-min argmin.
// -------------------------------------------------------------------------
__global__ __launch_bounds__(256) void merge_argmin(const float* __restrict__ pbest,
                                                    const int* __restrict__ pidx,
                                                    int* __restrict__ out)
{
    const long row = (long)blockIdx.x * 256 + threadIdx.x;
    float best = -INFINITY;
    int   bi   = 0;
    #pragma unroll
    for (int i = 0; i < NCHUNK; ++i) {
        float s = pbest[row * NCHUNK + i];
        if (s > best) { best = s; bi = pidx[row * NCHUNK + i]; }
    }
    out[row] = bi;
}

// -------------------------------------------------------------------------
extern "C" void kernel_launch(void* const* d_in, const int* in_sizes, int n_in,
                              void* d_out, int out_size, void* d_ws, size_t ws_size,
                              hipStream_t stream)
{
    const float* x  = (const float*)d_in[0];   // 8*2048*1024
    const float* W  = (const float*)d_in[1];   // 16*1024
    const float* cb = (const float*)d_in[2];   // 8192*16
    int* out = (int*)d_out;                    // 16384 int32

    char* ws = (char*)d_ws;
    unsigned short* zp  = (unsigned short*)ws;               // 1.5 MB
    unsigned short* cbp = (unsigned short*)(ws + 0x180000);  // 768 KB
    float* nhc  = (float*)(ws + 0x240000);                   // 32 KB
    unsigned short* wb = (unsigned short*)(ws + 0x248000);   // 96 KB
    float* zpart = (float*)(ws + 0x260000);                  // 4 MB (reused below)
    float* pbest = (float*)(ws + 0x260000);                  // 1 MB (after projB)
    int*   pidx  = (int*)  (ws + 0x360000);                  // 1 MB

    pack_w <<<24, 256, 0, stream>>>(W, wb);
    pack_cb<<<CS / 256, 256, 0, stream>>>(cb, cbp, nhc);
    projA  <<<ROWS / 16, 256, 0, stream>>>(x, wb, zpart);
    projB  <<<ROWS / 16, 256, 0, stream>>>(zpart, zp);
    dist_argmin<<<dim3(32, NCHUNK), 512, 0, stream>>>(zp, cbp, nhc, pbest, pidx);
    merge_argmin<<<ROWS / 256, 256, 0, stream>>>(pbest, pidx, out);
}

// Round 4
// 140.448 us; speedup vs baseline: 1.5113x; 1.0158x over previous
//
#include <hip/hip_runtime.h>
#include <math.h>

#define D      1024
#define CD     16
#define CS     8192
#define ROWS   16384   // B*L
#define LN_EPS 1e-5f
#define KCHUNK 512            // codes per dist chunk
#define NCHUNK (CS / KCHUNK)  // 16

typedef __attribute__((ext_vector_type(8))) short short8;
typedef __attribute__((ext_vector_type(4))) float f32x4;

__device__ inline unsigned short bf16_rne(float v) {
    unsigned u = __float_as_uint(v);
    unsigned r = u + 0x7FFFu + ((u >> 16) & 1u);
    return (unsigned short)(r >> 16);
}
__device__ inline short8 ld8(const unsigned short* p) { return *(const short8*)p; }

// exact 3-term bf16 split: v = a + b + c, dropped residual ~2^-27 rel
__device__ inline void split3(float v, unsigned short& a, unsigned short& b, unsigned short& c) {
    unsigned u = __float_as_uint(v);
    unsigned r = u + 0x7FFFu + ((u >> 16) & 1u);
    a = (unsigned short)(r >> 16);
    float r1 = v - __uint_as_float(r & 0xFFFF0000u);     // exact
    unsigned u1 = __float_as_uint(r1);
    unsigned r1b = u1 + 0x7FFFu + ((u1 >> 16) & 1u);
    b = (unsigned short)(r1b >> 16);
    float r2 = r1 - __uint_as_float(r1b & 0xFFFF0000u);  // exact
    c = bf16_rne(r2);
}

// -------------------------------------------------------------------------
// pack: blockIdx < 32 -> codebook 3-term split (48 bf16/code) + -0.5||c||^2;
//       blockIdx >= 32 -> W 3-term split in MFMA-B-frag stream order:
//       wb[((gk*3+term)*64 + lane)*8 + j] = W_t[n=lane&15][gk*32+(lane>>4)*8+j]
// -------------------------------------------------------------------------
__global__ __launch_bounds__(256) void pack_all(const float* __restrict__ W,
                                                const float* __restrict__ cb,
                                                unsigned short* __restrict__ wb,
                                                unsigned short* __restrict__ cbp,
                                                float* __restrict__ nhc)
{
    const int t = threadIdx.x;
    if (blockIdx.x < 32) {
        int k = blockIdx.x * 256 + t;          // 0..8191
        const float* c = cb + (long)k * CD;
        unsigned short* o = cbp + (long)k * 48;
        float csq = 0.f;
        #pragma unroll
        for (int d = 0; d < 16; ++d) {
            float v = c[d];
            csq = fmaf(v, v, csq);
            unsigned short h0, h1, h2;
            split3(v, h0, h1, h2);
            o[d] = h0; o[16 + d] = h1; o[32 + d] = h2;
        }
        nhc[k] = -0.5f * csq;
    } else {
        int tid = (blockIdx.x - 32) * 256 + t; // 0..6143
        int gk   = tid / 192;
        int rem  = tid % 192;
        int term = rem >> 6;
        int L    = rem & 63;
        int n = L & 15, q = L >> 4;
        const float* src = W + n * D + gk * 32 + q * 8;
        unsigned short* dst = wb + (size_t)tid * 8;
        #pragma unroll
        for (int j = 0; j < 8; ++j) {
            unsigned short h0, h1, h2;
            split3(src[j], h0, h1, h2);
            dst[j] = term == 0 ? h0 : (term == 1 ? h1 : h2);
        }
    }
}

// -------------------------------------------------------------------------
// proj_ln: z = LayerNorm(x @ W^T) fused, emitted as 3-term bf16 split.
// Block = 4 waves = 2 row-tiles x 2 K-halves (512 k each). Grid 512 -> 2
// blocks/CU, 8 waves/CU. Each wave: 16 kk steps of 6 MFMAs (exact 3-term
// split both sides; products >= 2^-16 kept, dropped <= 2^-24).
// K-halves combined via 2KB LDS; LN over the 16 channels of each output row
// (lanes of one quad) via shfl_xor; split3 + store zp in dist A-frag order.
// -------------------------------------------------------------------------
__global__ __launch_bounds__(256, 4) void proj_ln(const float* __restrict__ x,
                                                  const unsigned short* __restrict__ wb,
                                                  unsigned short* __restrict__ zp)
{
    __shared__ float part[2][64][4];   // [tile][lane][r]
    const int t = threadIdx.x;
    const int L = t & 63;
    const int w = t >> 6;
    const int tb = w & 1;              // tile within block
    const int kh = w >> 1;             // K half
    const int rt = blockIdx.x * 2 + tb;
    const int n = L & 15, q = L >> 4;

    const float* xrow = x + (size_t)(rt * 16 + n) * D + kh * 512 + q * 8;
    const unsigned short* wbase = wb + (size_t)(kh * 16) * 1536;

    f32x4 acc = {0.f, 0.f, 0.f, 0.f};
    #pragma unroll 4
    for (int kk = 0; kk < 16; ++kk) {
        float4 xa = *(const float4*)(xrow + kk * 32);
        float4 xb = *(const float4*)(xrow + kk * 32 + 4);
        const unsigned short* wp = wbase + (size_t)kk * 1536 + L * 8;
        short8 w0 = ld8(wp);
        short8 w1 = ld8(wp + 512);
        short8 w2 = ld8(wp + 1024);
        float vs[8] = {xa.x, xa.y, xa.z, xa.w, xb.x, xb.y, xb.z, xb.w};
        short8 x0, x1, x2;
        #pragma unroll
        for (int j = 0; j < 8; ++j) {
            unsigned short h0, h1, h2;
            split3(vs[j], h0, h1, h2);
            x0[j] = (short)h0; x1[j] = (short)h1; x2[j] = (short)h2;
        }
        acc = __builtin_amdgcn_mfma_f32_16x16x32_bf16(x0, w0, acc, 0, 0, 0);
        acc = __builtin_amdgcn_mfma_f32_16x16x32_bf16(x0, w1, acc, 0, 0, 0);
        acc = __builtin_amdgcn_mfma_f32_16x16x32_bf16(x1, w0, acc, 0, 0, 0);
        acc = __builtin_amdgcn_mfma_f32_16x16x32_bf16(x1, w1, acc, 0, 0, 0);
        acc = __builtin_amdgcn_mfma_f32_16x16x32_bf16(x0, w2, acc, 0, 0, 0);
        acc = __builtin_amdgcn_mfma_f32_16x16x32_bf16(x2, w0, acc, 0, 0, 0);
    }

    if (kh == 1) {
        #pragma unroll
        for (int r = 0; r < 4; ++r) part[tb][L][r] = acc[r];
    }
    __syncthreads();
    if (kh == 0) {
        // C/D layout: col n = channel (lane&15), row = q*4 + r
        #pragma unroll
        for (int r = 0; r < 4; ++r) {
            float zv = acc[r] + part[tb][L][r];
            float s = zv;
            for (int m = 1; m < 16; m <<= 1) s += __shfl_xor(s, m, 64);
            float mu = s * (1.f / 16.f);
            float dd = zv - mu;
            float v2 = dd * dd;
            for (int m = 1; m < 16; m <<= 1) v2 += __shfl_xor(v2, m, 64);
            float var = v2 * (1.f / 16.f);
            float zn = dd / sqrtf(var + LN_EPS);
            unsigned short h0, h1, h2;
            split3(zn, h0, h1, h2);
            unsigned short* zr = zp + (size_t)(rt * 16 + q * 4 + r) * 48;
            zr[n] = h0; zr[16 + n] = h1; zr[32 + n] = h2;
        }
    }
}

// -------------------------------------------------------------------------
// dist_argmin: score = z.c - 0.5||c||^2 (argmin d2 == argmax score).
// Exact 6-product split via 3 MFMAs per 16x16 tile, half-swaps on the A side
// (register-only, loaded once): a1=[z0|z1].b1=[c0|c1] -> z0c0+z1c1;
// a2=[z1|z0].b1 -> z1c0+z0c1; a3=[z2|z0].b3=[c0|c2] -> z2c0+z0c2.
// Only 2 ds_read_b128 per tt; bias enters as the C operand of the 1st MFMA.
// Block = 8 waves x 4 row-tiles; grid 32x16 = 2 blocks/CU, one generation.
// -------------------------------------------------------------------------
__global__ __launch_bounds__(512, 4) void dist_argmin(const unsigned short* __restrict__ zp,
                                                      const unsigned short* __restrict__ cbp,
                                                      const float* __restrict__ nhc,
                                                      float* __restrict__ pbest,
                                                      int* __restrict__ pidx)
{
    __shared__ __align__(16) unsigned short cl[KCHUNK * 48];  // 48 KB
    __shared__ float ql[KCHUNK];                              // 2 KB
    const int t = threadIdx.x;
    const int kbase = blockIdx.y * KCHUNK;

    {
        float4* dst = (float4*)cl;
        const float4* src = (const float4*)(cbp + (size_t)kbase * 48);
        #pragma unroll
        for (int i = 0; i < 6; ++i) dst[t + i * 512] = src[t + i * 512];
        if (t < KCHUNK / 4) ((float4*)ql)[t] = ((const float4*)(nhc + kbase))[t];
    }
    __syncthreads();

    const int L = t & 63;
    const int w = t >> 6;
    const int n = L & 15;    // code col (B n) / z row (A m)
    const int q = L >> 4;

    const int oa2 = (q * 8 + 16) & 31;                 // [z1|z0]
    const int oa3 = q < 2 ? 32 + q * 8 : (q - 2) * 8;  // [z2|z0]
    const int ob3 = q < 2 ? q * 8 : 16 + q * 8;        // [c0|c2]

    short8 a1[4], a2[4], a3[4];
    const int rt0 = blockIdx.x * 32 + w * 4;
    #pragma unroll
    for (int j = 0; j < 4; ++j) {
        const unsigned short* zr = zp + (size_t)((rt0 + j) * 16 + n) * 48;
        a1[j] = ld8(zr + q * 8);
        a2[j] = ld8(zr + oa2);
        a3[j] = ld8(zr + oa3);
    }

    float best[4][4];
    int   bi[4][4];
    #pragma unroll
    for (int j = 0; j < 4; ++j)
        #pragma unroll
        for (int r = 0; r < 4; ++r) { best[j][r] = -INFINITY; bi[j][r] = 0; }

    for (int tt = 0; tt < KCHUNK / 16; ++tt) {
        const unsigned short* cb_t = cl + (size_t)(tt * 16 + n) * 48;
        short8 b1 = ld8(cb_t + q * 8);
        short8 b3 = ld8(cb_t + ob3);
        float bneg = ql[tt * 16 + n];
        f32x4 bias = {bneg, bneg, bneg, bneg};
        int code = kbase + tt * 16 + n;
        f32x4 acc[4];
        #pragma unroll
        for (int j = 0; j < 4; ++j)
            acc[j] = __builtin_amdgcn_mfma_f32_16x16x32_bf16(a1[j], b1, bias, 0, 0, 0);
        #pragma unroll
        for (int j = 0; j < 4; ++j)
            acc[j] = __builtin_amdgcn_mfma_f32_16x16x32_bf16(a2[j], b1, acc[j], 0, 0, 0);
        #pragma unroll
        for (int j = 0; j < 4; ++j)
            acc[j] = __builtin_amdgcn_mfma_f32_16x16x32_bf16(a3[j], b3, acc[j], 0, 0, 0);
        #pragma unroll
        for (int j = 0; j < 4; ++j)
            #pragma unroll
            for (int r = 0; r < 4; ++r)
                if (acc[j][r] > best[j][r]) { best[j][r] = acc[j][r]; bi[j][r] = code; }
    }

    #pragma unroll
    for (int mask = 1; mask < 16; mask <<= 1) {
        #pragma unroll
        for (int j = 0; j < 4; ++j)
            #pragma unroll
            for (int r = 0; r < 4; ++r) {
                float s2 = __shfl_xor(best[j][r], mask, 64);
                int   i2 = __shfl_xor(bi[j][r], mask, 64);
                if (s2 > best[j][r] || (s2 == best[j][r] && i2 < bi[j][r])) {
                    best[j][r] = s2; bi[j][r] = i2;
                }
            }
    }
    if (n == 0) {
        #pragma unroll
        for (int j = 0; j < 4; ++j)
            #pragma unroll
            for (int r = 0; r < 4; ++r) {
                int row = (rt0 + j) * 16 + q * 4 + r;
                pbest[(size_t)row * NCHUNK + blockIdx.y] = best[j][r];
                pidx [(size_t)row * NCHUNK + blockIdx.y] = bi[j][r];
            }
    }
}

// -------------------------------------------------------------------------
// merge: fold 16 partials/row; ascending chunk order + strict '>' keeps the
// earliest winner -> matches np first-min argmin.
// -------------------------------------------------------------------------
__global__ __launch_bounds__(256) void merge_argmin(const float* __restrict__ pbest,
                                                    const int* __restrict__ pidx,
                                                    int* __restrict__ out)
{
    const long row = (long)blockIdx.x * 256 + threadIdx.x;
    float best = -INFINITY;
    int   bi   = 0;
    #pragma unroll
    for (int i = 0; i < NCHUNK; ++i) {
        float s = pbest[row * NCHUNK + i];
        if (s > best) { best = s; bi = pidx[row * NCHUNK + i]; }
    }
    out[row] = bi;
}

// -------------------------------------------------------------------------
extern "C" void kernel_launch(void* const* d_in, const int* in_sizes, int n_in,
                              void* d_out, int out_size, void* d_ws, size_t ws_size,
                              hipStream_t stream)
{
    const float* x  = (const float*)d_in[0];   // 8*2048*1024
    const float* W  = (const float*)d_in[1];   // 16*1024
    const float* cb = (const float*)d_in[2];   // 8192*16
    int* out = (int*)d_out;                    // 16384 int32

    char* ws = (char*)d_ws;
    unsigned short* zp  = (unsigned short*)ws;               // 1.5 MB
    unsigned short* cbp = (unsigned short*)(ws + 0x180000);  // 768 KB
    float* nhc  = (float*)(ws + 0x240000);                   // 32 KB
    unsigned short* wb = (unsigned short*)(ws + 0x248000);   // 96 KB
    float* pbest = (float*)(ws + 0x260000);                  // 1 MB
    int*   pidx  = (int*)  (ws + 0x360000);                  // 1 MB

    pack_all<<<56, 256, 0, stream>>>(W, cb, wb, cbp, nhc);
    proj_ln <<<ROWS / 32, 256, 0, stream>>>(x, wb, zp);
    dist_argmin<<<dim3(32, NCHUNK), 512, 0, stream>>>(zp, cbp, nhc, pbest, pidx);
    merge_argmin<<<ROWS / 256, 256, 0, stream>>>(pbest, pidx, out);
}

// Round 5
// 139.129 us; speedup vs baseline: 1.5256x; 1.0095x over previous
//
#include <hip/hip_runtime.h>
#include <math.h>

#define D      1024
#define CD     16
#define CS     8192
#define ROWS   16384   // B*L
#define LN_EPS 1e-5f
#define KCHUNK 512            // codes per dist chunk
#define NCHUNK (CS / KCHUNK)  // 16

typedef __attribute__((ext_vector_type(8))) short short8;
typedef __attribute__((ext_vector_type(4))) float f32x4;

__device__ inline unsigned short bf16_rne(float v) {
    unsigned u = __float_as_uint(v);
    unsigned r = u + 0x7FFFu + ((u >> 16) & 1u);
    return (unsigned short)(r >> 16);
}
__device__ inline short8 ld8(const unsigned short* p) { return *(const short8*)p; }

// exact 3-term bf16 split: v = a + b + c, dropped residual ~2^-27 rel
__device__ inline void split3(float v, unsigned short& a, unsigned short& b, unsigned short& c) {
    unsigned u = __float_as_uint(v);
    unsigned r = u + 0x7FFFu + ((u >> 16) & 1u);
    a = (unsigned short)(r >> 16);
    float r1 = v - __uint_as_float(r & 0xFFFF0000u);     // exact
    unsigned u1 = __float_as_uint(r1);
    unsigned r1b = u1 + 0x7FFFu + ((u1 >> 16) & 1u);
    b = (unsigned short)(r1b >> 16);
    float r2 = r1 - __uint_as_float(r1b & 0xFFFF0000u);  // exact
    c = bf16_rne(r2);
}

// -------------------------------------------------------------------------
// pack: blockIdx < 32 -> codebook 3-term split (48 bf16/code) + -0.5||c||^2;
//       blockIdx >= 32 -> W 3-term split in MFMA-B-frag stream order:
//       wb[((gk*3+term)*64 + lane)*8 + j] = W_t[n=lane&15][gk*32+(lane>>4)*8+j]
// -------------------------------------------------------------------------
__global__ __launch_bounds__(256) void pack_all(const float* __restrict__ W,
                                                const float* __restrict__ cb,
                                                unsigned short* __restrict__ wb,
                                                unsigned short* __restrict__ cbp,
                                                float* __restrict__ nhc)
{
    const int t = threadIdx.x;
    if (blockIdx.x < 32) {
        int k = blockIdx.x * 256 + t;          // 0..8191
        const float* c = cb + (long)k * CD;
        unsigned short* o = cbp + (long)k * 48;
        float csq = 0.f;
        #pragma unroll
        for (int d = 0; d < 16; ++d) {
            float v = c[d];
            csq = fmaf(v, v, csq);
            unsigned short h0, h1, h2;
            split3(v, h0, h1, h2);
            o[d] = h0; o[16 + d] = h1; o[32 + d] = h2;
        }
        nhc[k] = -0.5f * csq;
    } else {
        int tid = (blockIdx.x - 32) * 256 + t; // 0..6143
        int gk   = tid / 192;
        int rem  = tid % 192;
        int term = rem >> 6;
        int L    = rem & 63;
        int n = L & 15, q = L >> 4;
        const float* src = W + n * D + gk * 32 + q * 8;
        unsigned short* dst = wb + (size_t)tid * 8;
        #pragma unroll
        for (int j = 0; j < 8; ++j) {
            unsigned short h0, h1, h2;
            split3(src[j], h0, h1, h2);
            dst[j] = term == 0 ? h0 : (term == 1 ? h1 : h2);
        }
    }
}

// -------------------------------------------------------------------------
// proj_ln: z = LayerNorm(x @ W^T) fused, emitted as 3-term bf16 split.
// Block = 4 waves = 1 row-tile x 4 K-quarters (256 k each). Grid 1024 ->
// 4 blocks/CU, 16 waves/CU, exactly one resident generation.
// Per wave: 8 kk steps of 6 MFMAs (exact 3-term split both sides), split
// across TWO independent accumulator chains for MFMA-latency hiding.
// K-quarters combined via 3KB LDS; LN over 16 channels (quad lanes) by
// shfl_xor; split3 + store zp in dist A-frag order.
// -------------------------------------------------------------------------
__global__ __launch_bounds__(256, 4) void proj_ln(const float* __restrict__ x,
                                                  const unsigned short* __restrict__ wb,
                                                  unsigned short* __restrict__ zp)
{
    __shared__ float part[3][64][4];   // waves 1..3 deposit here
    const int t = threadIdx.x;
    const int L = t & 63;
    const int kq = t >> 6;             // K-quarter
    const int rt = blockIdx.x;         // row-tile
    const int n = L & 15, q = L >> 4;

    const float* xrow = x + (size_t)(rt * 16 + n) * D + kq * 256 + q * 8;
    const unsigned short* wbase = wb + (size_t)(kq * 8) * 1536;

    f32x4 acc0 = {0.f, 0.f, 0.f, 0.f};
    f32x4 acc1 = {0.f, 0.f, 0.f, 0.f};
    #pragma unroll
    for (int kk = 0; kk < 8; ++kk) {
        float4 xa = *(const float4*)(xrow + kk * 32);
        float4 xb = *(const float4*)(xrow + kk * 32 + 4);
        const unsigned short* wp = wbase + (size_t)kk * 1536 + L * 8;
        short8 w0 = ld8(wp);
        short8 w1 = ld8(wp + 512);
        short8 w2 = ld8(wp + 1024);
        float vs[8] = {xa.x, xa.y, xa.z, xa.w, xb.x, xb.y, xb.z, xb.w};
        short8 x0, x1, x2;
        #pragma unroll
        for (int j = 0; j < 8; ++j) {
            unsigned short h0, h1, h2;
            split3(vs[j], h0, h1, h2);
            x0[j] = (short)h0; x1[j] = (short)h1; x2[j] = (short)h2;
        }
        // two independent chains (exact products >= 2^-24 kept on each)
        acc0 = __builtin_amdgcn_mfma_f32_16x16x32_bf16(x0, w0, acc0, 0, 0, 0);
        acc1 = __builtin_amdgcn_mfma_f32_16x16x32_bf16(x0, w1, acc1, 0, 0, 0);
        acc0 = __builtin_amdgcn_mfma_f32_16x16x32_bf16(x1, w0, acc0, 0, 0, 0);
        acc1 = __builtin_amdgcn_mfma_f32_16x16x32_bf16(x1, w1, acc1, 0, 0, 0);
        acc0 = __builtin_amdgcn_mfma_f32_16x16x32_bf16(x0, w2, acc0, 0, 0, 0);
        acc1 = __builtin_amdgcn_mfma_f32_16x16x32_bf16(x2, w0, acc1, 0, 0, 0);
    }

    if (kq != 0) {
        #pragma unroll
        for (int r = 0; r < 4; ++r) part[kq - 1][L][r] = acc0[r] + acc1[r];
    }
    __syncthreads();
    if (kq == 0) {
        // C/D layout: col n = channel (lane&15), row = q*4 + r
        #pragma unroll
        for (int r = 0; r < 4; ++r) {
            float zv = acc0[r] + acc1[r] + part[0][L][r] + part[1][L][r] + part[2][L][r];
            float s = zv;
            for (int m = 1; m < 16; m <<= 1) s += __shfl_xor(s, m, 64);
            float mu = s * (1.f / 16.f);
            float dd = zv - mu;
            float v2 = dd * dd;
            for (int m = 1; m < 16; m <<= 1) v2 += __shfl_xor(v2, m, 64);
            float var = v2 * (1.f / 16.f);
            float zn = dd / sqrtf(var + LN_EPS);
            unsigned short h0, h1, h2;
            split3(zn, h0, h1, h2);
            unsigned short* zr = zp + (size_t)(rt * 16 + q * 4 + r) * 48;
            zr[n] = h0; zr[16 + n] = h1; zr[32 + n] = h2;
        }
    }
}

// -------------------------------------------------------------------------
// dist_argmin: score = z.c - 0.5||c||^2 (argmin d2 == argmax score).
// Exact 6-product split via 3 MFMAs per 16x16 tile, half-swaps on the A side
// (register-only): a1=[z0|z1].b1=[c0|c1]; a2=[z1|z0].b1; a3=[z2|z0].b3=[c0|c2].
// Bias enters as the C operand of the 1st MFMA. j=2 row-tiles/wave keeps
// VGPRs ~75 (no spill at launch_bounds(512,4) = 128 cap). Block = 8 waves
// covering 16 row-tiles; grid 64x16, 2 blocks/CU, two generations.
// -------------------------------------------------------------------------
__global__ __launch_bounds__(512, 4) void dist_argmin(const unsigned short* __restrict__ zp,
                                                      const unsigned short* __restrict__ cbp,
                                                      const float* __restrict__ nhc,
                                                      float* __restrict__ pbest,
                                                      int* __restrict__ pidx)
{
    __shared__ __align__(16) unsigned short cl[KCHUNK * 48];  // 48 KB
    __shared__ float ql[KCHUNK];                              // 2 KB
    const int t = threadIdx.x;
    const int kbase = blockIdx.y * KCHUNK;

    {
        float4* dst = (float4*)cl;
        const float4* src = (const float4*)(cbp + (size_t)kbase * 48);
        #pragma unroll
        for (int i = 0; i < 6; ++i) dst[t + i * 512] = src[t + i * 512];
        if (t < KCHUNK / 4) ((float4*)ql)[t] = ((const float4*)(nhc + kbase))[t];
    }
    __syncthreads();

    const int L = t & 63;
    const int w = t >> 6;
    const int n = L & 15;    // code col (B n) / z row (A m)
    const int q = L >> 4;

    const int oa2 = (q * 8 + 16) & 31;                 // [z1|z0]
    const int oa3 = q < 2 ? 32 + q * 8 : (q - 2) * 8;  // [z2|z0]
    const int ob3 = q < 2 ? q * 8 : 16 + q * 8;        // [c0|c2]

    short8 a1[2], a2[2], a3[2];
    const int rt0 = blockIdx.x * 16 + w * 2;
    #pragma unroll
    for (int j = 0; j < 2; ++j) {
        const unsigned short* zr = zp + (size_t)((rt0 + j) * 16 + n) * 48;
        a1[j] = ld8(zr + q * 8);
        a2[j] = ld8(zr + oa2);
        a3[j] = ld8(zr + oa3);
    }

    float best[2][4];
    int   bi[2][4];
    #pragma unroll
    for (int j = 0; j < 2; ++j)
        #pragma unroll
        for (int r = 0; r < 4; ++r) { best[j][r] = -INFINITY; bi[j][r] = 0; }

    #pragma unroll 2
    for (int tt = 0; tt < KCHUNK / 16; ++tt) {
        const unsigned short* cb_t = cl + (size_t)(tt * 16 + n) * 48;
        short8 b1 = ld8(cb_t + q * 8);
        short8 b3 = ld8(cb_t + ob3);
        float bneg = ql[tt * 16 + n];
        f32x4 bias = {bneg, bneg, bneg, bneg};
        int code = kbase + tt * 16 + n;
        f32x4 acc[2];
        #pragma unroll
        for (int j = 0; j < 2; ++j)
            acc[j] = __builtin_amdgcn_mfma_f32_16x16x32_bf16(a1[j], b1, bias, 0, 0, 0);
        #pragma unroll
        for (int j = 0; j < 2; ++j)
            acc[j] = __builtin_amdgcn_mfma_f32_16x16x32_bf16(a2[j], b1, acc[j], 0, 0, 0);
        #pragma unroll
        for (int j = 0; j < 2; ++j)
            acc[j] = __builtin_amdgcn_mfma_f32_16x16x32_bf16(a3[j], b3, acc[j], 0, 0, 0);
        #pragma unroll
        for (int j = 0; j < 2; ++j)
            #pragma unroll
            for (int r = 0; r < 4; ++r)
                if (acc[j][r] > best[j][r]) { best[j][r] = acc[j][r]; bi[j][r] = code; }
    }

    #pragma unroll
    for (int mask = 1; mask < 16; mask <<= 1) {
        #pragma unroll
        for (int j = 0; j < 2; ++j)
            #pragma unroll
            for (int r = 0; r < 4; ++r) {
                float s2 = __shfl_xor(best[j][r], mask, 64);
                int   i2 = __shfl_xor(bi[j][r], mask, 64);
                if (s2 > best[j][r] || (s2 == best[j][r] && i2 < bi[j][r])) {
                    best[j][r] = s2; bi[j][r] = i2;
                }
            }
    }
    if (n == 0) {
        #pragma unroll
        for (int j = 0; j < 2; ++j)
            #pragma unroll
            for (int r = 0; r < 4; ++r) {
                int row = (rt0 + j) * 16 + q * 4 + r;
                pbest[(size_t)row * NCHUNK + blockIdx.y] = best[j][r];
                pidx [(size_t)row * NCHUNK + blockIdx.y] = bi[j][r];
            }
    }
}

// -------------------------------------------------------------------------
// merge: fold 16 partials/row; ascending chunk order + strict '>' keeps the
// earliest winner -> matches np first-min argmin.
// -------------------------------------------------------------------------
__global__ __launch_bounds__(256) void merge_argmin(const float* __restrict__ pbest,
                                                    const int* __restrict__ pidx,
                                                    int* __restrict__ out)
{
    const long row = (long)blockIdx.x * 256 + threadIdx.x;
    float best = -INFINITY;
    int   bi   = 0;
    #pragma unroll
    for (int i = 0; i < NCHUNK; ++i) {
        float s = pbest[row * NCHUNK + i];
        if (s > best) { best = s; bi = pidx[row * NCHUNK + i]; }
    }
    out[row] = bi;
}

// -------------------------------------------------------------------------
extern "C" void kernel_launch(void* const* d_in, const int* in_sizes, int n_in,
                              void* d_out, int out_size, void* d_ws, size_t ws_size,
                              hipStream_t stream)
{
    const float* x  = (const float*)d_in[0];   // 8*2048*1024
    const float* W  = (const float*)d_in[1];   // 16*1024
    const float* cb = (const float*)d_in[2];   // 8192*16
    int* out = (int*)d_out;                    // 16384 int32

    char* ws = (char*)d_ws;
    unsigned short* zp  = (unsigned short*)ws;               // 1.5 MB
    unsigned short* cbp = (unsigned short*)(ws + 0x180000);  // 768 KB
    float* nhc  = (float*)(ws + 0x240000);                   // 32 KB
    unsigned short* wb = (unsigned short*)(ws + 0x248000);   // 96 KB
    float* pbest = (float*)(ws + 0x260000);                  // 1 MB
    int*   pidx  = (int*)  (ws + 0x360000);                  // 1 MB

    pack_all<<<56, 256, 0, stream>>>(W, cb, wb, cbp, nhc);
    proj_ln <<<ROWS / 16, 256, 0, stream>>>(x, wb, zp);
    dist_argmin<<<dim3(ROWS / 256, NCHUNK), 512, 0, stream>>>(zp, cbp, nhc, pbest, pidx);
    merge_argmin<<<ROWS / 256, 256, 0, stream>>>(pbest, pidx, out);
}